// Round 1
// baseline (30427.390 us; speedup 1.0000x reference)
//
#include <hip/hip_runtime.h>
#include <math.h>

constexpr int cB = 64, cT = 600, cD = 512, cE = 640, cH = 1024, cA = 1024,
              cP = 1024, cV = 10025, cN = 64;
constexpr int cBT = cB * cT;       // 38400
constexpr int cKx = cE + cD;       // 1152
constexpr int cKr = cH + cE + cD;  // 2176

__device__ __forceinline__ float bfu(unsigned short s) {
  return __uint_as_float(((unsigned int)s) << 16);
}
__device__ __forceinline__ unsigned short f2bf(float f) {
  unsigned int x = __float_as_uint(f);
  x += 0x7fffu + ((x >> 16) & 1u);
  return (unsigned short)(x >> 16);
}
__device__ __forceinline__ float fsig(float x) { return 1.0f / (1.0f + __expf(-x)); }
__device__ __forceinline__ float ftanh(float x) {
  float e = __expf(2.0f * x);
  return 1.0f - 2.0f / (e + 1.0f);
}

// ---------------- precompute ----------------

__global__ __launch_bounds__(256) void cast_kernel(const float* __restrict__ in,
                                                   unsigned short* __restrict__ out) {
  int i = blockIdx.x * 256 + threadIdx.x;  // indexes float4
  float4 v = reinterpret_cast<const float4*>(in)[i];
  ushort4 o;
  o.x = f2bf(v.x); o.y = f2bf(v.y); o.z = f2bf(v.z); o.w = f2bf(v.w);
  reinterpret_cast<ushort4*>(out)[i] = o;
}

__global__ __launch_bounds__(256) void fert_kernel(const float* __restrict__ enc,
                                                   const float* __restrict__ W_fert,
                                                   float* __restrict__ inv_fert) {
  int wave = threadIdx.x >> 6, lane = threadIdx.x & 63;
  int row = blockIdx.x * 4 + wave;
  const float* r = enc + (size_t)row * cD;
  float s = 0.0f;
#pragma unroll
  for (int i = 0; i < 8; ++i) s += r[lane + 64 * i] * W_fert[lane + 64 * i];
#pragma unroll
  for (int o = 32; o; o >>= 1) s += __shfl_xor(s, o);
  if (lane == 0) inv_fert[row] = 1.0f / (1.0f + __expf(-s));
}

#define GEMM_INNER                                                                      \
  _Pragma("unroll") for (int kk = 0; kk < 32; ++kk) {                                   \
    const float4 xv = *reinterpret_cast<const float4*>(&Xs[kk][ty * 4]);                \
    const float4 wv = *reinterpret_cast<const float4*>(&Ws[kk][tx * 4]);                \
    acc[0][0] += xv.x * wv.x; acc[0][1] += xv.x * wv.y;                                 \
    acc[0][2] += xv.x * wv.z; acc[0][3] += xv.x * wv.w;                                 \
    acc[1][0] += xv.y * wv.x; acc[1][1] += xv.y * wv.y;                                 \
    acc[1][2] += xv.y * wv.z; acc[1][3] += xv.y * wv.w;                                 \
    acc[2][0] += xv.z * wv.x; acc[2][1] += xv.z * wv.y;                                 \
    acc[2][2] += xv.z * wv.z; acc[2][3] += xv.z * wv.w;                                 \
    acc[3][0] += xv.w * wv.x; acc[3][1] += xv.w * wv.y;                                 \
    acc[3][2] += xv.w * wv.z; acc[3][3] += xv.w * wv.w;                                 \
  }

// enc_ctx[m, a] = enc[m,:] . W_enc[a,:] + b_enc[a], stored bf16
__global__ __launch_bounds__(256) void encctx_kernel(const float* __restrict__ enc,
                                                     const float* __restrict__ W_enc,
                                                     const float* __restrict__ b_enc,
                                                     unsigned short* __restrict__ out) {
  __shared__ __align__(16) float Xs[32][68];
  __shared__ __align__(16) float Ws[32][68];
  int tid = threadIdx.x;
  int m0 = blockIdx.y * 64;
  int n0 = blockIdx.x * 64;
  int tx = tid & 15, ty = tid >> 4;
  float acc[4][4] = {};
  for (int k0 = 0; k0 < cD; k0 += 32) {
#pragma unroll
    for (int p = 0; p < 2; ++p) {
      int qq = tid + 256 * p;
      int r = qq >> 3, c4 = (qq & 7) * 4;
      float4 v = *reinterpret_cast<const float4*>(&enc[(size_t)(m0 + r) * cD + k0 + c4]);
      Xs[c4][r] = v.x; Xs[c4 + 1][r] = v.y; Xs[c4 + 2][r] = v.z; Xs[c4 + 3][r] = v.w;
      float4 w = *reinterpret_cast<const float4*>(&W_enc[(size_t)(n0 + r) * cD + k0 + c4]);
      Ws[c4][r] = w.x; Ws[c4 + 1][r] = w.y; Ws[c4 + 2][r] = w.z; Ws[c4 + 3][r] = w.w;
    }
    __syncthreads();
    GEMM_INNER
    __syncthreads();
  }
#pragma unroll
  for (int r = 0; r < 4; ++r) {
    int m = m0 + ty * 4 + r;
#pragma unroll
    for (int c = 0; c < 4; ++c) {
      int n = n0 + tx * 4 + c;
      out[(size_t)m * cA + n] = f2bf(acc[r][c] + b_enc[n]);
    }
  }
}

// ---------------- per-step kernels ----------------

// gates[b, jj] for jj in [0,3072): i (W rows 0..1023), g (rows 2048..3071), o (rows 3072..4095)
__global__ __launch_bounds__(256) void gates_kernel(const float* __restrict__ W_ih,
                                                    const float* __restrict__ b_ih,
                                                    const float* __restrict__ b_hh,
                                                    const float* __restrict__ embed,
                                                    const int* __restrict__ labels,
                                                    const float* __restrict__ ctx,
                                                    float* __restrict__ gates, int t) {
  __shared__ __align__(16) float Xs[32][68];
  __shared__ __align__(16) float Ws[32][68];
  int tid = threadIdx.x;
  int n0 = blockIdx.x * 64;                // jj tile
  int woff = (n0 >= cH) ? cH : 0;          // map jj -> W_ih row
  int tx = tid & 15, ty = tid >> 4;
  float acc[4][4] = {};
  for (int k0 = 0; k0 < cKx; k0 += 32) {
#pragma unroll
    for (int p = 0; p < 8; ++p) {
      int el = tid + 256 * p;
      int b = el >> 5, kl = el & 31;
      int k = k0 + kl;
      float v;
      if (k < cE) {
        v = (t == 0) ? 0.0f : embed[(size_t)labels[b * cN + t - 1] * cE + k];
      } else {
        v = ctx[b * cD + (k - cE)];
      }
      Xs[kl][b] = v;
    }
#pragma unroll
    for (int p = 0; p < 2; ++p) {
      int qq = tid + 256 * p;
      int r = qq >> 3, c4 = (qq & 7) * 4;
      float4 w = *reinterpret_cast<const float4*>(
          &W_ih[(size_t)(n0 + r + woff) * cKx + k0 + c4]);
      Ws[c4][r] = w.x; Ws[c4 + 1][r] = w.y; Ws[c4 + 2][r] = w.z; Ws[c4 + 3][r] = w.w;
    }
    __syncthreads();
    GEMM_INNER
    __syncthreads();
  }
#pragma unroll
  for (int r = 0; r < 4; ++r) {
    int b = ty * 4 + r;
#pragma unroll
    for (int c = 0; c < 4; ++c) {
      int jj = n0 + tx * 4 + c;
      gates[b * 3 * cH + jj] = acc[r][c] + b_ih[jj + woff] + b_hh[jj + woff];
    }
  }
}

// h = 0.05*hprev + 0.95*( sig(o)*tanh(sig(i)*tanh(g)) );  q = h @ W_s.T
__global__ __launch_bounds__(256) void hq_kernel(const float* __restrict__ gates,
                                                 const float* __restrict__ hprev,
                                                 const float* __restrict__ W_s,
                                                 float* __restrict__ hcur,
                                                 float* __restrict__ qout,
                                                 float* __restrict__ s_seq, int t) {
  __shared__ __align__(16) float Xs[32][68];
  __shared__ __align__(16) float Ws[32][68];
  int tid = threadIdx.x;
  int n0 = blockIdx.x * 64;  // a tile
  int tx = tid & 15, ty = tid >> 4;
  float acc[4][4] = {};
  for (int k0 = 0; k0 < cH; k0 += 32) {
#pragma unroll
    for (int p = 0; p < 8; ++p) {
      int el = tid + 256 * p;
      int b = el >> 5, jl = el & 31;
      int j = k0 + jl;
      float gi = gates[b * 3 * cH + j];
      float gg = gates[b * 3 * cH + cH + j];
      float go = gates[b * 3 * cH + 2 * cH + j];
      float hnew = fsig(go) * ftanh(fsig(gi) * ftanh(gg));
      float h = 0.05f * hprev[b * cH + j] + 0.95f * hnew;
      Xs[jl][b] = h;
      if (blockIdx.x == 0) {
        hcur[b * cH + j] = h;
        s_seq[((size_t)b * cN + t) * cH + j] = h;
      }
    }
#pragma unroll
    for (int p = 0; p < 2; ++p) {
      int qq = tid + 256 * p;
      int r = qq >> 3, c4 = (qq & 7) * 4;
      float4 w = *reinterpret_cast<const float4*>(&W_s[(size_t)(n0 + r) * cH + k0 + c4]);
      Ws[c4][r] = w.x; Ws[c4 + 1][r] = w.y; Ws[c4 + 2][r] = w.z; Ws[c4 + 3][r] = w.w;
    }
    __syncthreads();
    GEMM_INNER
    __syncthreads();
  }
#pragma unroll
  for (int r = 0; r < 4; ++r)
#pragma unroll
    for (int c = 0; c < 4; ++c)
      qout[(ty * 4 + r) * cA + n0 + tx * 4 + c] = acc[r][c];
}

// e[b,t] = sum_a v[a]*tanh(enc_ctx[b,t,a] + q[b,a] + accum[b,t]*W_fb[a]); -inf if masked
__global__ __launch_bounds__(256) void energy_kernel(
    const unsigned short* __restrict__ enc_ctx, const float* __restrict__ q,
    const float* __restrict__ v_att, const float* __restrict__ W_fb,
    const float* __restrict__ accum, const int* __restrict__ slen,
    float* __restrict__ e_out) {
  __shared__ float q_s[cA];
  __shared__ float v_s[cA];
  __shared__ float f_s[cA];
  int b = blockIdx.y;
  int t0 = blockIdx.x * 16;
  int tid = threadIdx.x;
  for (int i = tid; i < cA; i += 256) {
    q_s[i] = q[b * cA + i];
    v_s[i] = v_att[i];
    f_s[i] = W_fb[i];
  }
  __syncthreads();
  int wave = tid >> 6, lane = tid & 63;
  int len = slen[b];
#pragma unroll
  for (int p = 0; p < 4; ++p) {
    int t = t0 + p * 4 + wave;
    if (t >= cT) continue;
    if (t >= len) {
      if (lane == 0) e_out[b * cT + t] = -__builtin_inff();
      continue;
    }
    float fb = accum[b * cT + t];
    const unsigned short* row = enc_ctx + ((size_t)(b * cT + t)) * cA;
    float acc = 0.0f;
#pragma unroll
    for (int k = 0; k < 8; ++k) {
      int a = 2 * lane + 128 * k;
      unsigned int u = *reinterpret_cast<const unsigned int*>(&row[a]);
      float c0 = __uint_as_float((u & 0xffffu) << 16);
      float c1 = __uint_as_float(u & 0xffff0000u);
      acc += v_s[a] * ftanh(c0 + q_s[a] + fb * f_s[a]);
      acc += v_s[a + 1] * ftanh(c1 + q_s[a + 1] + fb * f_s[a + 1]);
    }
#pragma unroll
    for (int o = 32; o; o >>= 1) acc += __shfl_xor(acc, o);
    if (lane == 0) e_out[b * cT + t] = acc;
  }
}

// softmax over e[b,:], ctx[b,d] = sum_t w[t]*enc[b,t,d], accum += w*inv_fert*0.5
__global__ __launch_bounds__(256) void ctxsm_kernel(const float* __restrict__ e,
                                                    const unsigned short* __restrict__ enc_bf,
                                                    const float* __restrict__ inv_fert,
                                                    float* __restrict__ accum,
                                                    float* __restrict__ ctxbuf,
                                                    float* __restrict__ ctx_seq, int t_step) {
  __shared__ float w_s[cT];
  __shared__ float red[8];
  int b = blockIdx.y;
  int dblk = blockIdx.x;
  int tid = threadIdx.x;
  int wave = tid >> 6, lane = tid & 63;
  const float* eb = e + b * cT;
  float m = -__builtin_inff();
  for (int t = tid; t < cT; t += 256) m = fmaxf(m, eb[t]);
#pragma unroll
  for (int o = 32; o; o >>= 1) m = fmaxf(m, __shfl_xor(m, o));
  if (lane == 0) red[wave] = m;
  __syncthreads();
  m = fmaxf(fmaxf(red[0], red[1]), fmaxf(red[2], red[3]));
  float s = 0.0f;
  for (int t = tid; t < cT; t += 256) {
    float w = __expf(eb[t] - m);
    w_s[t] = w;
    s += w;
  }
#pragma unroll
  for (int o = 32; o; o >>= 1) s += __shfl_xor(s, o);
  if (lane == 0) red[4 + wave] = s;
  __syncthreads();
  float inv_l = 1.0f / (red[4] + red[5] + red[6] + red[7]);
  int d = dblk * 256 + tid;  // 0..511
  const unsigned short* ebase = enc_bf + (size_t)b * cT * cD;
  float acc = 0.0f;
  for (int t = 0; t < cT; t += 8) {
    float v0 = bfu(ebase[(size_t)(t + 0) * cD + d]);
    float v1 = bfu(ebase[(size_t)(t + 1) * cD + d]);
    float v2 = bfu(ebase[(size_t)(t + 2) * cD + d]);
    float v3 = bfu(ebase[(size_t)(t + 3) * cD + d]);
    float v4 = bfu(ebase[(size_t)(t + 4) * cD + d]);
    float v5 = bfu(ebase[(size_t)(t + 5) * cD + d]);
    float v6 = bfu(ebase[(size_t)(t + 6) * cD + d]);
    float v7 = bfu(ebase[(size_t)(t + 7) * cD + d]);
    acc += w_s[t] * v0 + w_s[t + 1] * v1 + w_s[t + 2] * v2 + w_s[t + 3] * v3;
    acc += w_s[t + 4] * v4 + w_s[t + 5] * v5 + w_s[t + 6] * v6 + w_s[t + 7] * v7;
  }
  acc *= inv_l;
  ctxbuf[b * cD + d] = acc;
  ctx_seq[((size_t)b * cN + t_step) * cD + d] = acc;
  if (dblk == 0) {
    for (int t = tid; t < cT; t += 256)
      accum[b * cT + t] += w_s[t] * inv_l * inv_fert[b * cT + t] * 0.5f;
  }
}

// ---------------- post ----------------

// mo[row, pc] = maxout2( concat(s,emb,ctx) @ W_r.T + b_r )
__global__ __launch_bounds__(256) void readout_kernel(const float* __restrict__ s_seq,
                                                      const float* __restrict__ ctx_seq,
                                                      const float* __restrict__ embed,
                                                      const int* __restrict__ labels,
                                                      const float* __restrict__ W_r,
                                                      const float* __restrict__ b_r,
                                                      float* __restrict__ mo) {
  __shared__ __align__(16) float Xs[32][68];
  __shared__ __align__(16) float Ws[32][68];
  int tid = threadIdx.x;
  int m0 = blockIdx.y * 64;
  int n0 = blockIdx.x * 64;
  int tx = tid & 15, ty = tid >> 4;
  float acc[4][4] = {};
  for (int k0 = 0; k0 < cKr; k0 += 32) {
#pragma unroll
    for (int p = 0; p < 2; ++p) {
      int qq = tid + 256 * p;
      int r = qq >> 3, c4 = (qq & 7) * 4;
      int row = m0 + r;
      int k = k0 + c4;
      float4 v;
      if (k < cH) {
        v = *reinterpret_cast<const float4*>(&s_seq[(size_t)row * cH + k]);
      } else if (k < cH + cE) {
        int n = row & 63;
        if (n == 0) {
          v = make_float4(0.f, 0.f, 0.f, 0.f);
        } else {
          int lab = labels[(row >> 6) * cN + n - 1];
          v = *reinterpret_cast<const float4*>(&embed[(size_t)lab * cE + (k - cH)]);
        }
      } else {
        v = *reinterpret_cast<const float4*>(&ctx_seq[(size_t)row * cD + (k - cH - cE)]);
      }
      Xs[c4][r] = v.x; Xs[c4 + 1][r] = v.y; Xs[c4 + 2][r] = v.z; Xs[c4 + 3][r] = v.w;
      float4 w = *reinterpret_cast<const float4*>(&W_r[(size_t)(n0 + r) * cKr + k]);
      Ws[c4][r] = w.x; Ws[c4 + 1][r] = w.y; Ws[c4 + 2][r] = w.z; Ws[c4 + 3][r] = w.w;
    }
    __syncthreads();
    GEMM_INNER
    __syncthreads();
  }
#pragma unroll
  for (int r = 0; r < 4; ++r) {
    int row = m0 + ty * 4 + r;
    float v0 = acc[r][0] + b_r[n0 + tx * 4 + 0];
    float v1 = acc[r][1] + b_r[n0 + tx * 4 + 1];
    float v2 = acc[r][2] + b_r[n0 + tx * 4 + 2];
    float v3 = acc[r][3] + b_r[n0 + tx * 4 + 3];
    int pc = (n0 + tx * 4) >> 1;
    mo[(size_t)row * (cP / 2) + pc] = fmaxf(v0, v1);
    mo[(size_t)row * (cP / 2) + pc + 1] = fmaxf(v2, v3);
  }
}

__global__ __launch_bounds__(256) void logits_kernel(const float* __restrict__ mo,
                                                     const float* __restrict__ W_o,
                                                     const float* __restrict__ b_o,
                                                     float* __restrict__ out) {
  __shared__ __align__(16) float Xs[32][68];
  __shared__ __align__(16) float Ws[32][68];
  int tid = threadIdx.x;
  int m0 = blockIdx.y * 64;
  int n0 = blockIdx.x * 64;
  int tx = tid & 15, ty = tid >> 4;
  float acc[4][4] = {};
  for (int k0 = 0; k0 < cP / 2; k0 += 32) {
#pragma unroll
    for (int p = 0; p < 2; ++p) {
      int qq = tid + 256 * p;
      int r = qq >> 3, c4 = (qq & 7) * 4;
      float4 v = *reinterpret_cast<const float4*>(&mo[(size_t)(m0 + r) * (cP / 2) + k0 + c4]);
      Xs[c4][r] = v.x; Xs[c4 + 1][r] = v.y; Xs[c4 + 2][r] = v.z; Xs[c4 + 3][r] = v.w;
      int vrow = n0 + r;
      float4 w = (vrow < cV)
                     ? *reinterpret_cast<const float4*>(&W_o[(size_t)vrow * (cP / 2) + k0 + c4])
                     : make_float4(0.f, 0.f, 0.f, 0.f);
      Ws[c4][r] = w.x; Ws[c4 + 1][r] = w.y; Ws[c4 + 2][r] = w.z; Ws[c4 + 3][r] = w.w;
    }
    __syncthreads();
    GEMM_INNER
    __syncthreads();
  }
#pragma unroll
  for (int r = 0; r < 4; ++r) {
    int row = m0 + ty * 4 + r;
#pragma unroll
    for (int c = 0; c < 4; ++c) {
      int vcol = n0 + tx * 4 + c;
      if (vcol < cV) out[(size_t)row * cV + vcol] = acc[r][c] + b_o[vcol];
    }
  }
}

// ---------------- launcher ----------------

extern "C" void kernel_launch(void* const* d_in, const int* in_sizes, int n_in,
                              void* d_out, int out_size, void* d_ws, size_t ws_size,
                              hipStream_t stream) {
  (void)in_sizes; (void)n_in; (void)out_size; (void)ws_size;
  const float* enc    = (const float*)d_in[0];
  const int*   labels = (const int*)d_in[1];
  const int*   slen   = (const int*)d_in[2];
  const float* embed  = (const float*)d_in[3];
  const float* W_ih   = (const float*)d_in[4];
  const float* b_ih   = (const float*)d_in[5];
  const float* b_hh   = (const float*)d_in[6];
  const float* W_s    = (const float*)d_in[7];
  const float* W_enc  = (const float*)d_in[8];
  const float* b_enc  = (const float*)d_in[9];
  const float* v_att  = (const float*)d_in[10];
  const float* W_fert = (const float*)d_in[11];
  const float* W_fb   = (const float*)d_in[12];
  const float* W_r    = (const float*)d_in[13];
  const float* b_r    = (const float*)d_in[14];
  const float* W_o    = (const float*)d_in[15];
  const float* b_o    = (const float*)d_in[16];
  float* out = (float*)d_out;

  char* ws = (char*)d_ws;
  size_t off = 0;
  auto alloc = [&](size_t bytes) -> char* {
    char* p = ws + off;
    off = (off + bytes + 255) & ~(size_t)255;
    return p;
  };
  unsigned short* enc_ctx = (unsigned short*)alloc((size_t)cBT * cA * 2);
  unsigned short* enc_bf  = (unsigned short*)alloc((size_t)cBT * cD * 2);
  float* inv_fert = (float*)alloc((size_t)cBT * 4);
  float* accum    = (float*)alloc((size_t)cBT * 4);
  float* ebuf     = (float*)alloc((size_t)cBT * 4);
  float* hA       = (float*)alloc((size_t)cB * cH * 4);
  float* hB       = (float*)alloc((size_t)cB * cH * 4);
  float* ctxb     = (float*)alloc((size_t)cB * cD * 4);
  float* qb       = (float*)alloc((size_t)cB * cA * 4);
  float* gates    = (float*)alloc((size_t)cB * 3 * cH * 4);
  float* s_seq    = (float*)alloc((size_t)cB * cN * cH * 4);
  float* ctx_seq  = (float*)alloc((size_t)cB * cN * cD * 4);
  float* mo       = (float*)alloc((size_t)cB * cN * (cP / 2) * 4);

  hipMemsetAsync(accum, 0, (size_t)cBT * 4, stream);
  hipMemsetAsync(ctxb, 0, (size_t)cB * cD * 4, stream);
  hipMemsetAsync(hA, 0, (size_t)cB * cH * 4, stream);

  cast_kernel<<<(cBT * cD) / 1024, 256, 0, stream>>>(enc, enc_bf);
  fert_kernel<<<cBT / 4, 256, 0, stream>>>(enc, W_fert, inv_fert);
  encctx_kernel<<<dim3(cA / 64, cBT / 64), 256, 0, stream>>>(enc, W_enc, b_enc, enc_ctx);

  for (int t = 0; t < cN; ++t) {
    float* hprev = (t & 1) ? hB : hA;
    float* hcur  = (t & 1) ? hA : hB;
    gates_kernel<<<3 * cH / 64, 256, 0, stream>>>(W_ih, b_ih, b_hh, embed, labels, ctxb,
                                                  gates, t);
    hq_kernel<<<cA / 64, 256, 0, stream>>>(gates, hprev, W_s, hcur, qb, s_seq, t);
    energy_kernel<<<dim3((cT + 15) / 16, cB), 256, 0, stream>>>(enc_ctx, qb, v_att, W_fb,
                                                                accum, slen, ebuf);
    ctxsm_kernel<<<dim3(cD / 256, cB), 256, 0, stream>>>(ebuf, enc_bf, inv_fert, accum,
                                                         ctxb, ctx_seq, t);
  }

  readout_kernel<<<dim3(cP / 64, (cB * cN) / 64), 256, 0, stream>>>(s_seq, ctx_seq, embed,
                                                                    labels, W_r, b_r, mo);
  logits_kernel<<<dim3((cV + 63) / 64, (cB * cN) / 64), 256, 0, stream>>>(mo, W_o, b_o, out);
}

// Round 2
// 29164.157 us; speedup vs baseline: 1.0433x; 1.0433x over previous
//
#include <hip/hip_runtime.h>
#include <math.h>

constexpr int cB = 64, cT = 600, cD = 512, cE = 640, cH = 1024, cA = 1024,
              cP = 1024, cV = 10025, cN = 64;
constexpr int cBT = cB * cT;       // 38400
constexpr int cKx = cE + cD;       // 1152
constexpr int cKr = cH + cE + cD;  // 2176
constexpr int cM  = cB * cN;       // 4096
constexpr int cVp = 10112;         // V padded to 79*128

typedef __attribute__((ext_vector_type(8))) short bf16x8;
typedef __attribute__((ext_vector_type(4))) float f32x4;

__device__ __forceinline__ float bfu(unsigned short s) {
  return __uint_as_float(((unsigned int)s) << 16);
}
__device__ __forceinline__ unsigned short f2bf(float f) {
  unsigned int x = __float_as_uint(f);
  x += 0x7fffu + ((x >> 16) & 1u);
  return (unsigned short)(x >> 16);
}
__device__ __forceinline__ float fsig(float x) { return 1.0f / (1.0f + __expf(-x)); }
__device__ __forceinline__ float ftanh(float x) {
  float e = __expf(2.0f * x);
  return 1.0f - 2.0f / (e + 1.0f);
}

#define GLD(g, s)                                                          \
  __builtin_amdgcn_global_load_lds(                                       \
      (const __attribute__((address_space(1))) void*)(g),                 \
      (__attribute__((address_space(3))) void*)(s), 16, 0, 0)

__device__ __forceinline__ int xcd_swizzle(int bid, int nwg) {
  int q = nwg >> 3, r = nwg & 7;
  int x = bid & 7, loc = bid >> 3;
  return (x < r ? x * (q + 1) : r * (q + 1) + (x - r) * q) + loc;
}

// ---------------- precompute / casts ----------------

__global__ __launch_bounds__(256) void cast_kernel(const float* __restrict__ in,
                                                   unsigned short* __restrict__ out) {
  int i = blockIdx.x * 256 + threadIdx.x;  // indexes float4
  float4 v = reinterpret_cast<const float4*>(in)[i];
  ushort4 o;
  o.x = f2bf(v.x); o.y = f2bf(v.y); o.z = f2bf(v.z); o.w = f2bf(v.w);
  reinterpret_cast<ushort4*>(out)[i] = o;
}

__global__ __launch_bounds__(256) void cast_hl_kernel(const float* __restrict__ in,
                                                      unsigned short* __restrict__ hi,
                                                      unsigned short* __restrict__ lo) {
  int i = blockIdx.x * 256 + threadIdx.x;
  float4 v = reinterpret_cast<const float4*>(in)[i];
  ushort4 h, l;
  h.x = f2bf(v.x); h.y = f2bf(v.y); h.z = f2bf(v.z); h.w = f2bf(v.w);
  l.x = f2bf(v.x - bfu(h.x)); l.y = f2bf(v.y - bfu(h.y));
  l.z = f2bf(v.z - bfu(h.z)); l.w = f2bf(v.w - bfu(h.w));
  reinterpret_cast<ushort4*>(hi)[i] = h;
  reinterpret_cast<ushort4*>(lo)[i] = l;
}

// W_o [10025][512] -> padded [10112][512] hi/lo
__global__ __launch_bounds__(256) void cast_wo_kernel(const float* __restrict__ in,
                                                      unsigned short* __restrict__ hi,
                                                      unsigned short* __restrict__ lo) {
  int idx = blockIdx.x * 256 + threadIdx.x;  // per float4 of padded buffer
  int row = idx >> 7;
  int k = (idx & 127) * 4;
  float4 v = (row < cV) ? *reinterpret_cast<const float4*>(&in[(size_t)row * cD + k])
                        : make_float4(0.f, 0.f, 0.f, 0.f);
  ushort4 h, l;
  h.x = f2bf(v.x); h.y = f2bf(v.y); h.z = f2bf(v.z); h.w = f2bf(v.w);
  l.x = f2bf(v.x - bfu(h.x)); l.y = f2bf(v.y - bfu(h.y));
  l.z = f2bf(v.z - bfu(h.z)); l.w = f2bf(v.w - bfu(h.w));
  reinterpret_cast<ushort4*>(hi)[idx] = h;
  reinterpret_cast<ushort4*>(lo)[idx] = l;
}

__global__ __launch_bounds__(256) void fert_kernel(const float* __restrict__ enc,
                                                   const float* __restrict__ W_fert,
                                                   float* __restrict__ inv_fert) {
  int wave = threadIdx.x >> 6, lane = threadIdx.x & 63;
  int row = blockIdx.x * 4 + wave;
  const float* r = enc + (size_t)row * cD;
  float s = 0.0f;
#pragma unroll
  for (int i = 0; i < 8; ++i) s += r[lane + 64 * i] * W_fert[lane + 64 * i];
#pragma unroll
  for (int o = 32; o; o >>= 1) s += __shfl_xor(s, o);
  if (lane == 0) inv_fert[row] = 1.0f / (1.0f + __expf(-s));
}

// concat(s_seq, emb, ctx_seq) -> Ar hi/lo bf16 [4096][2176]
__global__ __launch_bounds__(256) void build_ar_kernel(
    const float* __restrict__ s_seq, const float* __restrict__ ctx_seq,
    const float* __restrict__ embed, const int* __restrict__ labels,
    unsigned short* __restrict__ Ah, unsigned short* __restrict__ Al) {
  int idx = blockIdx.x * 256 + threadIdx.x;  // per 4 elements
  int row = idx / (cKr / 4);
  int k = (idx % (cKr / 4)) * 4;
  float4 v;
  if (k < cH) {
    v = *reinterpret_cast<const float4*>(&s_seq[(size_t)row * cH + k]);
  } else if (k < cH + cE) {
    int n = row & 63;
    if (n == 0) {
      v = make_float4(0.f, 0.f, 0.f, 0.f);
    } else {
      int lab = labels[(row >> 6) * cN + n - 1];
      v = *reinterpret_cast<const float4*>(&embed[(size_t)lab * cE + (k - cH)]);
    }
  } else {
    v = *reinterpret_cast<const float4*>(&ctx_seq[(size_t)row * cD + (k - cH - cE)]);
  }
  ushort4 h, l;
  h.x = f2bf(v.x); h.y = f2bf(v.y); h.z = f2bf(v.z); h.w = f2bf(v.w);
  l.x = f2bf(v.x - bfu(h.x)); l.y = f2bf(v.y - bfu(h.y));
  l.z = f2bf(v.z - bfu(h.z)); l.w = f2bf(v.w - bfu(h.w));
  *reinterpret_cast<ushort4*>(&Ah[(size_t)row * cKr + k]) = h;
  *reinterpret_cast<ushort4*>(&Al[(size_t)row * cKr + k]) = l;
}

// ---------------- MFMA GEMMs ----------------

// enc_ctx = enc_bf @ W_enc_bf^T + b_enc  -> bf16 [38400][1024]
__global__ __launch_bounds__(256) void mfma_encctx(const unsigned short* __restrict__ A,
                                                   const unsigned short* __restrict__ Bm,
                                                   const float* __restrict__ bias,
                                                   unsigned short* __restrict__ C) {
  __shared__ unsigned short sA[4096], sB[4096];  // [128][32]
  constexpr int nbx = cA / 128;  // 8
  int bid = xcd_swizzle(blockIdx.x, gridDim.x);
  int by = bid / nbx, bx = bid % nbx;
  int tid = threadIdx.x;
  int w = tid >> 6, l = tid & 63;
  int m0 = by * 128, n0 = bx * 128;
  int wr = w >> 1, wc = w & 1;
  f32x4 acc[4][4] = {};
  int srow = tid >> 2, scol = (tid & 3) * 8;
  for (int k0 = 0; k0 < cD; k0 += 32) {
    __syncthreads();
    GLD(&A[(size_t)(m0 + srow) * cD + k0 + scol], &sA[tid * 8]);
    GLD(&A[(size_t)(m0 + 64 + srow) * cD + k0 + scol], &sA[2048 + tid * 8]);
    GLD(&Bm[(size_t)(n0 + srow) * cD + k0 + scol], &sB[tid * 8]);
    GLD(&Bm[(size_t)(n0 + 64 + srow) * cD + k0 + scol], &sB[2048 + tid * 8]);
    __syncthreads();
    int rA = wr * 64 + (l & 15);
    int rB = wc * 64 + (l & 15);
    int kg = (l >> 4) * 8;
    bf16x8 a[4], b[4];
#pragma unroll
    for (int i = 0; i < 4; ++i) a[i] = *(const bf16x8*)&sA[(rA + i * 16) * 32 + kg];
#pragma unroll
    for (int j = 0; j < 4; ++j) b[j] = *(const bf16x8*)&sB[(rB + j * 16) * 32 + kg];
#pragma unroll
    for (int i = 0; i < 4; ++i)
#pragma unroll
      for (int j = 0; j < 4; ++j)
        acc[i][j] = __builtin_amdgcn_mfma_f32_16x16x32_bf16(a[i], b[j], acc[i][j], 0, 0, 0);
  }
  int rbase = m0 + wr * 64 + ((l >> 4) * 4);
  int cbase = n0 + wc * 64 + (l & 15);
  float bv[4];
#pragma unroll
  for (int j = 0; j < 4; ++j) bv[j] = bias[cbase + j * 16];
#pragma unroll
  for (int i = 0; i < 4; ++i)
#pragma unroll
    for (int q = 0; q < 4; ++q) {
      int row = rbase + i * 16 + q;
#pragma unroll
      for (int j = 0; j < 4; ++j)
        C[(size_t)row * cA + cbase + j * 16] = f2bf(acc[i][j][q] + bv[j]);
    }
}

// C = (Ah+Al) @ (Bh+Bl)^T via 3 MFMA products. EP=0: readout (bias+maxout->bf16 hi/lo),
// EP=1: logits (bias, col<cV, fp32 out)
template <int EP>
__global__ __launch_bounds__(256) void mfma_gemm3(
    const unsigned short* __restrict__ Ah, const unsigned short* __restrict__ Al,
    const unsigned short* __restrict__ Bh, const unsigned short* __restrict__ Bl,
    const float* __restrict__ bias, void* __restrict__ outv, int K, int nbx) {
  __shared__ unsigned short sAh[4096], sAl[4096], sBh[4096], sBl[4096];
  int bid = xcd_swizzle(blockIdx.x, gridDim.x);
  int by = bid / nbx, bx = bid % nbx;
  int tid = threadIdx.x;
  int w = tid >> 6, l = tid & 63;
  int m0 = by * 128, n0 = bx * 128;
  int wr = w >> 1, wc = w & 1;
  f32x4 acc[4][4] = {};
  int srow = tid >> 2, scol = (tid & 3) * 8;
  for (int k0 = 0; k0 < K; k0 += 32) {
    __syncthreads();
    GLD(&Ah[(size_t)(m0 + srow) * K + k0 + scol], &sAh[tid * 8]);
    GLD(&Ah[(size_t)(m0 + 64 + srow) * K + k0 + scol], &sAh[2048 + tid * 8]);
    GLD(&Al[(size_t)(m0 + srow) * K + k0 + scol], &sAl[tid * 8]);
    GLD(&Al[(size_t)(m0 + 64 + srow) * K + k0 + scol], &sAl[2048 + tid * 8]);
    GLD(&Bh[(size_t)(n0 + srow) * K + k0 + scol], &sBh[tid * 8]);
    GLD(&Bh[(size_t)(n0 + 64 + srow) * K + k0 + scol], &sBh[2048 + tid * 8]);
    GLD(&Bl[(size_t)(n0 + srow) * K + k0 + scol], &sBl[tid * 8]);
    GLD(&Bl[(size_t)(n0 + 64 + srow) * K + k0 + scol], &sBl[2048 + tid * 8]);
    __syncthreads();
    int rA = wr * 64 + (l & 15);
    int rB = wc * 64 + (l & 15);
    int kg = (l >> 4) * 8;
    bf16x8 bh[4], bl[4];
#pragma unroll
    for (int j = 0; j < 4; ++j) {
      bh[j] = *(const bf16x8*)&sBh[(rB + j * 16) * 32 + kg];
      bl[j] = *(const bf16x8*)&sBl[(rB + j * 16) * 32 + kg];
    }
#pragma unroll
    for (int i = 0; i < 4; ++i) {
      bf16x8 ah = *(const bf16x8*)&sAh[(rA + i * 16) * 32 + kg];
      bf16x8 al = *(const bf16x8*)&sAl[(rA + i * 16) * 32 + kg];
#pragma unroll
      for (int j = 0; j < 4; ++j) {
        acc[i][j] = __builtin_amdgcn_mfma_f32_16x16x32_bf16(ah, bh[j], acc[i][j], 0, 0, 0);
        acc[i][j] = __builtin_amdgcn_mfma_f32_16x16x32_bf16(ah, bl[j], acc[i][j], 0, 0, 0);
        acc[i][j] = __builtin_amdgcn_mfma_f32_16x16x32_bf16(al, bh[j], acc[i][j], 0, 0, 0);
      }
    }
  }
  int rbase = m0 + wr * 64 + ((l >> 4) * 4);
  int cbase = n0 + wc * 64 + (l & 15);
  float bv[4];
#pragma unroll
  for (int j = 0; j < 4; ++j) {
    int col = cbase + j * 16;
    bv[j] = (EP == 1) ? (col < cV ? bias[col] : 0.0f) : bias[col];
  }
  if (EP == 0) {
    unsigned short* mo_h = (unsigned short*)outv;
    unsigned short* mo_l = mo_h + (size_t)cM * (cP / 2);
#pragma unroll
    for (int i = 0; i < 4; ++i)
#pragma unroll
      for (int q = 0; q < 4; ++q) {
        int row = rbase + i * 16 + q;
#pragma unroll
        for (int j = 0; j < 4; ++j) {
          float v = acc[i][j][q] + bv[j];
          float o = fmaxf(v, __shfl_xor(v, 1));
          if (!(l & 1)) {
            int ch = (cbase + j * 16) >> 1;
            unsigned short h = f2bf(o);
            mo_h[(size_t)row * (cP / 2) + ch] = h;
            mo_l[(size_t)row * (cP / 2) + ch] = f2bf(o - bfu(h));
          }
        }
      }
  } else {
    float* out = (float*)outv;
#pragma unroll
    for (int i = 0; i < 4; ++i)
#pragma unroll
      for (int q = 0; q < 4; ++q) {
        int row = rbase + i * 16 + q;
#pragma unroll
        for (int j = 0; j < 4; ++j) {
          int col = cbase + j * 16;
          if (col < cV) out[(size_t)row * cV + col] = acc[i][j][q] + bv[j];
        }
      }
  }
}

// ---------------- per-step kernels (unchanged from round 1) ----------------

#define GEMM_INNER                                                                      \
  _Pragma("unroll") for (int kk = 0; kk < 32; ++kk) {                                   \
    const float4 xv = *reinterpret_cast<const float4*>(&Xs[kk][ty * 4]);                \
    const float4 wv = *reinterpret_cast<const float4*>(&Ws[kk][tx * 4]);                \
    acc[0][0] += xv.x * wv.x; acc[0][1] += xv.x * wv.y;                                 \
    acc[0][2] += xv.x * wv.z; acc[0][3] += xv.x * wv.w;                                 \
    acc[1][0] += xv.y * wv.x; acc[1][1] += xv.y * wv.y;                                 \
    acc[1][2] += xv.y * wv.z; acc[1][3] += xv.y * wv.w;                                 \
    acc[2][0] += xv.z * wv.x; acc[2][1] += xv.z * wv.y;                                 \
    acc[2][2] += xv.z * wv.z; acc[2][3] += xv.z * wv.w;                                 \
    acc[3][0] += xv.w * wv.x; acc[3][1] += xv.w * wv.y;                                 \
    acc[3][2] += xv.w * wv.z; acc[3][3] += xv.w * wv.w;                                 \
  }

__global__ __launch_bounds__(256) void gates_kernel(const float* __restrict__ W_ih,
                                                    const float* __restrict__ b_ih,
                                                    const float* __restrict__ b_hh,
                                                    const float* __restrict__ embed,
                                                    const int* __restrict__ labels,
                                                    const float* __restrict__ ctx,
                                                    float* __restrict__ gates, int t) {
  __shared__ __align__(16) float Xs[32][68];
  __shared__ __align__(16) float Ws[32][68];
  int tid = threadIdx.x;
  int n0 = blockIdx.x * 64;
  int woff = (n0 >= cH) ? cH : 0;
  int tx = tid & 15, ty = tid >> 4;
  float acc[4][4] = {};
  for (int k0 = 0; k0 < cKx; k0 += 32) {
#pragma unroll
    for (int p = 0; p < 8; ++p) {
      int el = tid + 256 * p;
      int b = el >> 5, kl = el & 31;
      int k = k0 + kl;
      float v;
      if (k < cE) {
        v = (t == 0) ? 0.0f : embed[(size_t)labels[b * cN + t - 1] * cE + k];
      } else {
        v = ctx[b * cD + (k - cE)];
      }
      Xs[kl][b] = v;
    }
#pragma unroll
    for (int p = 0; p < 2; ++p) {
      int qq = tid + 256 * p;
      int r = qq >> 3, c4 = (qq & 7) * 4;
      float4 w = *reinterpret_cast<const float4*>(
          &W_ih[(size_t)(n0 + r + woff) * cKx + k0 + c4]);
      Ws[c4][r] = w.x; Ws[c4 + 1][r] = w.y; Ws[c4 + 2][r] = w.z; Ws[c4 + 3][r] = w.w;
    }
    __syncthreads();
    GEMM_INNER
    __syncthreads();
  }
#pragma unroll
  for (int r = 0; r < 4; ++r) {
    int b = ty * 4 + r;
#pragma unroll
    for (int c = 0; c < 4; ++c) {
      int jj = n0 + tx * 4 + c;
      gates[b * 3 * cH + jj] = acc[r][c] + b_ih[jj + woff] + b_hh[jj + woff];
    }
  }
}

__global__ __launch_bounds__(256) void hq_kernel(const float* __restrict__ gates,
                                                 const float* __restrict__ hprev,
                                                 const float* __restrict__ W_s,
                                                 float* __restrict__ hcur,
                                                 float* __restrict__ qout,
                                                 float* __restrict__ s_seq, int t) {
  __shared__ __align__(16) float Xs[32][68];
  __shared__ __align__(16) float Ws[32][68];
  int tid = threadIdx.x;
  int n0 = blockIdx.x * 64;
  int tx = tid & 15, ty = tid >> 4;
  float acc[4][4] = {};
  for (int k0 = 0; k0 < cH; k0 += 32) {
#pragma unroll
    for (int p = 0; p < 8; ++p) {
      int el = tid + 256 * p;
      int b = el >> 5, jl = el & 31;
      int j = k0 + jl;
      float gi = gates[b * 3 * cH + j];
      float gg = gates[b * 3 * cH + cH + j];
      float go = gates[b * 3 * cH + 2 * cH + j];
      float hnew = fsig(go) * ftanh(fsig(gi) * ftanh(gg));
      float h = 0.05f * hprev[b * cH + j] + 0.95f * hnew;
      Xs[jl][b] = h;
      if (blockIdx.x == 0) {
        hcur[b * cH + j] = h;
        s_seq[((size_t)b * cN + t) * cH + j] = h;
      }
    }
#pragma unroll
    for (int p = 0; p < 2; ++p) {
      int qq = tid + 256 * p;
      int r = qq >> 3, c4 = (qq & 7) * 4;
      float4 w = *reinterpret_cast<const float4*>(&W_s[(size_t)(n0 + r) * cH + k0 + c4]);
      Ws[c4][r] = w.x; Ws[c4 + 1][r] = w.y; Ws[c4 + 2][r] = w.z; Ws[c4 + 3][r] = w.w;
    }
    __syncthreads();
    GEMM_INNER
    __syncthreads();
  }
#pragma unroll
  for (int r = 0; r < 4; ++r)
#pragma unroll
    for (int c = 0; c < 4; ++c)
      qout[(ty * 4 + r) * cA + n0 + tx * 4 + c] = acc[r][c];
}

__global__ __launch_bounds__(256) void energy_kernel(
    const unsigned short* __restrict__ enc_ctx, const float* __restrict__ q,
    const float* __restrict__ v_att, const float* __restrict__ W_fb,
    const float* __restrict__ accum, const int* __restrict__ slen,
    float* __restrict__ e_out) {
  __shared__ float q_s[cA];
  __shared__ float v_s[cA];
  __shared__ float f_s[cA];
  int b = blockIdx.y;
  int t0 = blockIdx.x * 16;
  int tid = threadIdx.x;
  for (int i = tid; i < cA; i += 256) {
    q_s[i] = q[b * cA + i];
    v_s[i] = v_att[i];
    f_s[i] = W_fb[i];
  }
  __syncthreads();
  int wave = tid >> 6, lane = tid & 63;
  int len = slen[b];
#pragma unroll
  for (int p = 0; p < 4; ++p) {
    int t = t0 + p * 4 + wave;
    if (t >= cT) continue;
    if (t >= len) {
      if (lane == 0) e_out[b * cT + t] = -__builtin_inff();
      continue;
    }
    float fb = accum[b * cT + t];
    const unsigned short* row = enc_ctx + ((size_t)(b * cT + t)) * cA;
    float acc = 0.0f;
#pragma unroll
    for (int k = 0; k < 8; ++k) {
      int a = 2 * lane + 128 * k;
      unsigned int u = *reinterpret_cast<const unsigned int*>(&row[a]);
      float c0 = __uint_as_float((u & 0xffffu) << 16);
      float c1 = __uint_as_float(u & 0xffff0000u);
      acc += v_s[a] * ftanh(c0 + q_s[a] + fb * f_s[a]);
      acc += v_s[a + 1] * ftanh(c1 + q_s[a + 1] + fb * f_s[a + 1]);
    }
#pragma unroll
    for (int o = 32; o; o >>= 1) acc += __shfl_xor(acc, o);
    if (lane == 0) e_out[b * cT + t] = acc;
  }
}

__global__ __launch_bounds__(256) void ctxsm_kernel(const float* __restrict__ e,
                                                    const unsigned short* __restrict__ enc_bf,
                                                    const float* __restrict__ inv_fert,
                                                    float* __restrict__ accum,
                                                    float* __restrict__ ctxbuf,
                                                    float* __restrict__ ctx_seq, int t_step) {
  __shared__ float w_s[cT];
  __shared__ float red[8];
  int b = blockIdx.y;
  int dblk = blockIdx.x;
  int tid = threadIdx.x;
  int wave = tid >> 6, lane = tid & 63;
  const float* eb = e + b * cT;
  float m = -__builtin_inff();
  for (int t = tid; t < cT; t += 256) m = fmaxf(m, eb[t]);
#pragma unroll
  for (int o = 32; o; o >>= 1) m = fmaxf(m, __shfl_xor(m, o));
  if (lane == 0) red[wave] = m;
  __syncthreads();
  m = fmaxf(fmaxf(red[0], red[1]), fmaxf(red[2], red[3]));
  float s = 0.0f;
  for (int t = tid; t < cT; t += 256) {
    float w = __expf(eb[t] - m);
    w_s[t] = w;
    s += w;
  }
#pragma unroll
  for (int o = 32; o; o >>= 1) s += __shfl_xor(s, o);
  if (lane == 0) red[4 + wave] = s;
  __syncthreads();
  float inv_l = 1.0f / (red[4] + red[5] + red[6] + red[7]);
  int d = dblk * 256 + tid;
  const unsigned short* ebase = enc_bf + (size_t)b * cT * cD;
  float acc = 0.0f;
  for (int t = 0; t < cT; t += 8) {
    float v0 = bfu(ebase[(size_t)(t + 0) * cD + d]);
    float v1 = bfu(ebase[(size_t)(t + 1) * cD + d]);
    float v2 = bfu(ebase[(size_t)(t + 2) * cD + d]);
    float v3 = bfu(ebase[(size_t)(t + 3) * cD + d]);
    float v4 = bfu(ebase[(size_t)(t + 4) * cD + d]);
    float v5 = bfu(ebase[(size_t)(t + 5) * cD + d]);
    float v6 = bfu(ebase[(size_t)(t + 6) * cD + d]);
    float v7 = bfu(ebase[(size_t)(t + 7) * cD + d]);
    acc += w_s[t] * v0 + w_s[t + 1] * v1 + w_s[t + 2] * v2 + w_s[t + 3] * v3;
    acc += w_s[t + 4] * v4 + w_s[t + 5] * v5 + w_s[t + 6] * v6 + w_s[t + 7] * v7;
  }
  acc *= inv_l;
  ctxbuf[b * cD + d] = acc;
  ctx_seq[((size_t)b * cN + t_step) * cD + d] = acc;
  if (dblk == 0) {
    for (int t = tid; t < cT; t += 256)
      accum[b * cT + t] += w_s[t] * inv_l * inv_fert[b * cT + t] * 0.5f;
  }
}

// ---------------- launcher ----------------

extern "C" void kernel_launch(void* const* d_in, const int* in_sizes, int n_in,
                              void* d_out, int out_size, void* d_ws, size_t ws_size,
                              hipStream_t stream) {
  (void)in_sizes; (void)n_in; (void)out_size; (void)ws_size;
  const float* enc    = (const float*)d_in[0];
  const int*   labels = (const int*)d_in[1];
  const int*   slen   = (const int*)d_in[2];
  const float* embed  = (const float*)d_in[3];
  const float* W_ih   = (const float*)d_in[4];
  const float* b_ih   = (const float*)d_in[5];
  const float* b_hh   = (const float*)d_in[6];
  const float* W_s    = (const float*)d_in[7];
  const float* W_enc  = (const float*)d_in[8];
  const float* b_enc  = (const float*)d_in[9];
  const float* v_att  = (const float*)d_in[10];
  const float* W_fert = (const float*)d_in[11];
  const float* W_fb   = (const float*)d_in[12];
  const float* W_r    = (const float*)d_in[13];
  const float* b_r    = (const float*)d_in[14];
  const float* W_o    = (const float*)d_in[15];
  const float* b_o    = (const float*)d_in[16];
  float* out = (float*)d_out;

  char* ws = (char*)d_ws;
  size_t off = 0;
  auto alloc = [&](size_t bytes) -> char* {
    char* p = ws + off;
    off = (off + bytes + 255) & ~(size_t)255;
    return p;
  };
  unsigned short* enc_ctx = (unsigned short*)alloc((size_t)cBT * cA * 2);
  unsigned short* enc_bf  = (unsigned short*)alloc((size_t)cBT * cD * 2);
  unsigned short* wencb   = (unsigned short*)alloc((size_t)cA * cD * 2);
  float* inv_fert = (float*)alloc((size_t)cBT * 4);
  float* accum    = (float*)alloc((size_t)cBT * 4);
  float* ebuf     = (float*)alloc((size_t)cBT * 4);
  float* hA       = (float*)alloc((size_t)cB * cH * 4);
  float* hB       = (float*)alloc((size_t)cB * cH * 4);
  float* ctxb     = (float*)alloc((size_t)cB * cD * 4);
  float* qb       = (float*)alloc((size_t)cB * cA * 4);
  float* gates    = (float*)alloc((size_t)cB * 3 * cH * 4);
  float* s_seq    = (float*)alloc((size_t)cM * cH * 4);
  float* ctx_seq  = (float*)alloc((size_t)cM * cD * 4);
  unsigned short* Ar_h = (unsigned short*)alloc((size_t)cM * cKr * 2);
  unsigned short* Ar_l = (unsigned short*)alloc((size_t)cM * cKr * 2);
  unsigned short* Wr_h = (unsigned short*)alloc((size_t)cP * cKr * 2);
  unsigned short* Wr_l = (unsigned short*)alloc((size_t)cP * cKr * 2);
  unsigned short* mo_hl = (unsigned short*)alloc((size_t)2 * cM * (cP / 2) * 2);
  unsigned short* Wo_h = (unsigned short*)alloc((size_t)cVp * cD * 2);
  unsigned short* Wo_l = (unsigned short*)alloc((size_t)cVp * cD * 2);

  hipMemsetAsync(accum, 0, (size_t)cBT * 4, stream);
  hipMemsetAsync(ctxb, 0, (size_t)cB * cD * 4, stream);
  hipMemsetAsync(hA, 0, (size_t)cB * cH * 4, stream);

  cast_kernel<<<(cBT * cD) / 1024, 256, 0, stream>>>(enc, enc_bf);
  cast_kernel<<<(cA * cD) / 1024, 256, 0, stream>>>(W_enc, wencb);
  fert_kernel<<<cBT / 4, 256, 0, stream>>>(enc, W_fert, inv_fert);
  mfma_encctx<<<(cBT / 128) * (cA / 128), 256, 0, stream>>>(enc_bf, wencb, b_enc, enc_ctx);
  cast_hl_kernel<<<(cP * cKr) / 1024, 256, 0, stream>>>(W_r, Wr_h, Wr_l);
  cast_wo_kernel<<<(cVp * cD) / 1024, 256, 0, stream>>>(W_o, Wo_h, Wo_l);

  for (int t = 0; t < cN; ++t) {
    float* hprev = (t & 1) ? hB : hA;
    float* hcur  = (t & 1) ? hA : hB;
    gates_kernel<<<3 * cH / 64, 256, 0, stream>>>(W_ih, b_ih, b_hh, embed, labels, ctxb,
                                                  gates, t);
    hq_kernel<<<cA / 64, 256, 0, stream>>>(gates, hprev, W_s, hcur, qb, s_seq, t);
    energy_kernel<<<dim3((cT + 15) / 16, cB), 256, 0, stream>>>(enc_ctx, qb, v_att, W_fb,
                                                                accum, slen, ebuf);
    ctxsm_kernel<<<dim3(cD / 256, cB), 256, 0, stream>>>(ebuf, enc_bf, inv_fert, accum,
                                                         ctxb, ctx_seq, t);
  }

  build_ar_kernel<<<(cM * cKr) / 1024, 256, 0, stream>>>(s_seq, ctx_seq, embed, labels,
                                                         Ar_h, Ar_l);
  mfma_gemm3<0><<<(cM / 128) * (cP / 128), 256, 0, stream>>>(Ar_h, Ar_l, Wr_h, Wr_l, b_r,
                                                             (void*)mo_hl, cKr, cP / 128);
  unsigned short* mo_h = mo_hl;
  unsigned short* mo_l = mo_hl + (size_t)cM * (cP / 2);
  mfma_gemm3<1><<<(cM / 128) * (cVp / 128), 256, 0, stream>>>(mo_h, mo_l, Wo_h, Wo_l, b_o,
                                                              (void*)out, cP / 2, cVp / 128);
}